// Round 1
// baseline (2280.156 us; speedup 1.0000x reference)
//
#include <hip/hip_runtime.h>
#include <cstdint>

// SplineConv MeshEncoder: 3 layers, K=3 DIM=3 M=27, dims 3->64->64->64.
// Strategy: precompute per-edge 8-corner (kidx, w) once (edge_attr shared
// across layers), counting-sort edges by dst into CSR, then per layer run a
// fused kernel: one wave per 2 nodes, accumulate acc(27*C_in) in LDS from
// incoming edges, contract against W from cache, add root+bias, ReLU.

constexpr int MM = 27;

__global__ void count_kernel(const int* __restrict__ ei, int* __restrict__ count, int E) {
    int e = blockIdx.x * blockDim.x + threadIdx.x;
    if (e < E) atomicAdd(&count[ei[E + e]], 1);
}

// Single-block exclusive scan over N counts -> row_ptr[0..N], cursor copy.
__global__ void scan_kernel(const int* __restrict__ count, int* __restrict__ row_ptr,
                            int* __restrict__ cursor, int N) {
    __shared__ int sdata[1024];
    __shared__ int carry_s;
    if (threadIdx.x == 0) carry_s = 0;
    __syncthreads();
    for (int base = 0; base < N; base += 1024) {
        int i = base + (int)threadIdx.x;
        int v = (i < N) ? count[i] : 0;
        sdata[threadIdx.x] = v;
        __syncthreads();
        for (int off = 1; off < 1024; off <<= 1) {
            int t = (threadIdx.x >= (unsigned)off) ? sdata[threadIdx.x - off] : 0;
            __syncthreads();
            sdata[threadIdx.x] += t;
            __syncthreads();
        }
        int incl = sdata[threadIdx.x];
        int carry = carry_s;
        if (i < N) {
            row_ptr[i] = carry + incl - v;
            cursor[i]  = carry + incl - v;
        }
        __syncthreads();
        if (threadIdx.x == 1023) carry_s = carry + sdata[1023];
        __syncthreads();
    }
    if (threadIdx.x == 0) row_ptr[N] = carry_s;
}

// Per edge: compute 8 corner weights + flat kernel indices, write to
// dst-sorted position via atomic cursor.
__global__ void basis_sort_kernel(const int* __restrict__ ei, const float* __restrict__ attr,
                                  int* __restrict__ cursor, int* __restrict__ s_src,
                                  unsigned long long* __restrict__ s_kidx,
                                  float* __restrict__ s_w, int E) {
    int e = blockIdx.x * blockDim.x + threadIdx.x;
    if (e >= E) return;
    int src = ei[e];
    int dst = ei[E + e];
    float f[3]; int i0[3];
#pragma unroll
    for (int d = 0; d < 3; d++) {
        float pos = attr[e * 3 + d] * 2.0f;          // K-1 = 2
        float fl = floorf(pos);
        fl = fminf(fmaxf(fl, 0.0f), 1.0f);           // clip to [0, K-2]
        i0[d] = (int)fl;
        f[d] = pos - fl;
    }
    int p = atomicAdd(&cursor[dst], 1);
    s_src[p] = src;
    unsigned long long packed = 0;
#pragma unroll
    for (int c = 0; c < 8; c++) {
        float w = 1.0f;
        int kidx = 0;
        const int strides[3] = {1, 3, 9};
#pragma unroll
        for (int d = 0; d < 3; d++) {
            int off = (c >> d) & 1;
            w *= off ? f[d] : (1.0f - f[d]);
            kidx += (i0[d] + off) * strides[d];
        }
        packed |= ((unsigned long long)(kidx & 0xFF)) << (8 * c);
        s_w[(size_t)p * 8 + c] = w;
    }
    s_kidx[p] = packed;
}

// Fused layer: one wave (64 threads) per block handles NPB nodes.
// Phase A: accumulate acc[node][m*CIN+i] in LDS from CSR edge list.
// Phase B: out[n,o] = relu( (sum_k acc[n][k]*W[k][o]) / deg + x[n]@Wr[:,o] + b[o] )
template <int CIN>
__global__ __launch_bounds__(64) void layer_kernel(
    const float* __restrict__ h_in, const float* __restrict__ W,
    const float* __restrict__ Wr, const float* __restrict__ bias,
    const int* __restrict__ row_ptr, const int* __restrict__ s_src,
    const unsigned long long* __restrict__ s_kidx, const float* __restrict__ s_w,
    float* __restrict__ h_out, int N) {
    constexpr int KTOT = MM * CIN;   // 81 or 1728
    constexpr int NPB = 2;
    __shared__ float acc[NPB][KTOT];
    const int lane = threadIdx.x;
    const int n0 = blockIdx.x * NPB;

    // zero acc
#pragma unroll
    for (int g = 0; g < NPB; g++)
        for (int k = lane; k < KTOT; k += 64) acc[g][k] = 0.0f;
    __syncthreads();

    // Phase A: scatter-accumulate per node
    for (int g = 0; g < NPB; g++) {
        int n = n0 + g;
        if (n >= N) break;
        int rs = row_ptr[n], re = row_ptr[n + 1];
        for (int e = rs; e < re; e++) {
            int src = s_src[e];
            unsigned long long packed = s_kidx[e];
            float w[8];
#pragma unroll
            for (int c = 0; c < 8; c++) w[c] = s_w[(size_t)e * 8 + c];
            if (CIN == 64) {
                float xj = h_in[(size_t)src * 64 + lane];
#pragma unroll
                for (int c = 0; c < 8; c++) {
                    int kidx = (int)((packed >> (8 * c)) & 0xFF);
                    acc[g][kidx * 64 + lane] += w[c] * xj;
                }
            } else {
                if (lane < 24) {
                    int c = lane / 3, i = lane % 3;
                    float xj = h_in[(size_t)src * 3 + i];
                    int kidx = (int)((packed >> (8 * c)) & 0xFF);
                    acc[g][kidx * 3 + i] += w[c] * xj;
                }
            }
        }
    }
    __syncthreads();

    // Phase B: contraction with W, per output channel = lane
    float s[NPB];
#pragma unroll
    for (int g = 0; g < NPB; g++) s[g] = 0.0f;
#pragma unroll 4
    for (int k = 0; k < KTOT; k++) {
        float wv = W[(size_t)k * 64 + lane];
#pragma unroll
        for (int g = 0; g < NPB; g++) s[g] += acc[g][k] * wv;
    }

    float bv = bias[lane];
    for (int g = 0; g < NPB; g++) {
        int n = n0 + g;
        if (n >= N) break;
        int deg = row_ptr[n + 1] - row_ptr[n];
        float invd = (deg > 0) ? (1.0f / (float)deg) : 1.0f;
        float r = 0.0f;
#pragma unroll 4
        for (int i = 0; i < CIN; i++) r += h_in[(size_t)n * CIN + i] * Wr[i * 64 + lane];
        float o = s[g] * invd + r + bv;
        h_out[(size_t)n * 64 + lane] = fmaxf(o, 0.0f);
    }
}

extern "C" void kernel_launch(void* const* d_in, const int* in_sizes, int n_in,
                              void* d_out, int out_size, void* d_ws, size_t ws_size,
                              hipStream_t stream) {
    (void)n_in; (void)out_size; (void)ws_size;
    const float* x    = (const float*)d_in[0];
    const int*   ei   = (const int*)d_in[1];
    const float* attr = (const float*)d_in[2];
    const float* W0 = (const float*)d_in[3];
    const float* R0 = (const float*)d_in[4];
    const float* B0 = (const float*)d_in[5];
    const float* W1 = (const float*)d_in[6];
    const float* R1 = (const float*)d_in[7];
    const float* B1 = (const float*)d_in[8];
    const float* W2 = (const float*)d_in[9];
    const float* R2 = (const float*)d_in[10];
    const float* B2 = (const float*)d_in[11];
    const int N = in_sizes[0] / 3;
    const int E = in_sizes[1] / 2;

    char* ws = (char*)d_ws;
    size_t off = 0;
    auto alloc = [&](size_t bytes) {
        size_t cur = off;
        off = (off + bytes + 255) & ~(size_t)255;
        return cur;
    };
    int* row_ptr = (int*)(ws + alloc((size_t)(N + 1) * 4));
    int* count   = (int*)(ws + alloc((size_t)N * 4));
    int* cursor  = (int*)(ws + alloc((size_t)N * 4));
    int* s_src   = (int*)(ws + alloc((size_t)E * 4));
    unsigned long long* s_kidx = (unsigned long long*)(ws + alloc((size_t)E * 8));
    float* s_w   = (float*)(ws + alloc((size_t)E * 8 * 4));
    float* h_a   = (float*)(ws + alloc((size_t)N * 64 * 4));
    float* h_b   = (float*)(ws + alloc((size_t)N * 64 * 4));

    hipMemsetAsync(count, 0, (size_t)N * 4, stream);
    count_kernel<<<(E + 255) / 256, 256, 0, stream>>>(ei, count, E);
    scan_kernel<<<1, 1024, 0, stream>>>(count, row_ptr, cursor, N);
    basis_sort_kernel<<<(E + 255) / 256, 256, 0, stream>>>(ei, attr, cursor, s_src, s_kidx, s_w, E);

    int nblocks = (N + 1) / 2;
    layer_kernel<3><<<nblocks, 64, 0, stream>>>(x,   W0, R0, B0, row_ptr, s_src, s_kidx, s_w, h_a, N);
    layer_kernel<64><<<nblocks, 64, 0, stream>>>(h_a, W1, R1, B1, row_ptr, s_src, s_kidx, s_w, h_b, N);
    layer_kernel<64><<<nblocks, 64, 0, stream>>>(h_b, W2, R2, B2, row_ptr, s_src, s_kidx, s_w, (float*)d_out, N);
}